// Round 9
// baseline (76.890 us; speedup 1.0000x reference)
//
#include <hip/hip_runtime.h>
#include <hip/hip_bf16.h>

#define NPTS 16384
#define NNBR 32
#define CIN 16
#define COUT 16
#define NBASIS 16

// LDS f16 row stride 264 (528 B = 132 dw ≡ 4 mod 32): lanes t and t+8 alias
// 2-way on b128 reads -> free (m136).
#define WF_OS 264
#define ML_PS 264

typedef _Float16 half8 __attribute__((ext_vector_type(8)));
typedef float floatx4 __attribute__((ext_vector_type(4)));

// ws layout: xT16 (NPTS*16 f16, 512 KB) | coords4 (NPTS float4, 256 KB) |
//            Wf16 (4096 f16 in [o][b*16+i] order, 8 KB)
#define WS_XT 0
#define WS_C4 (NPTS * CIN)                  // in f16 units
#define WS_WF (WS_C4 + NPTS * 4 * 2)        // float4 = 8 f16 units per point

// Prep: transpose input -> xT16 [n][i] f16; coords -> coords4; block 0 also
// packs W -> Wf16 [o][b*16+i]. All reads/writes coalesced except tiny W.
__global__ __launch_bounds__(256) void prep_kernel(
        const float* __restrict__ input, const float* __restrict__ coords,
        const float* __restrict__ W, _Float16* __restrict__ ws) {
    const int n = blockIdx.x * 256 + threadIdx.x;
    // xT16: read coalesced along n per channel, write 32 B contiguous per lane
    _Float16 v[CIN];
    #pragma unroll
    for (int i = 0; i < CIN; ++i) v[i] = (_Float16)input[i * NPTS + n];
    *(half8*)&ws[WS_XT + n * CIN]     = *(half8*)&v[0];
    *(half8*)&ws[WS_XT + n * CIN + 8] = *(half8*)&v[8];
    // coords4
    float4* c4 = (float4*)&ws[WS_C4];
    c4[n] = make_float4(coords[n * 3 + 0], coords[n * 3 + 1], coords[n * 3 + 2], 0.0f);
    // Wf16 (block 0): thread (o,b) gathers i-row, writes 16 contiguous f16
    if (blockIdx.x == 0) {
        const int o = threadIdx.x >> 4, b = threadIdx.x & 15;
        _Float16 w[16];
        #pragma unroll
        for (int i = 0; i < CIN; ++i) w[i] = (_Float16)W[o * 256 + i * 16 + b];
        *(half8*)&ws[WS_WF + o * 256 + b * 16]     = *(half8*)&w[0];
        *(half8*)&ws[WS_WF + o * 256 + b * 16 + 8] = *(half8*)&w[8];
    }
}

// Conv: 256 threads = 16 points, 1024 blocks. ONE barrier: Wf staged at top
// (read only in Phase C), Phase B self-contained (loads nbr/mask/coords4/xT16
// directly from global; each group lane computes its own r and exp for b=t).
__global__ __launch_bounds__(256) void se3_conv_kernel(
        const _Float16* __restrict__ ws,
        const float* __restrict__ centers,   // (NBASIS,)
        const float* __restrict__ mask,      // (NPTS, NNBR) f32
        const int* __restrict__ neighbors,   // (NPTS, NNBR)
        float* __restrict__ out) {           // (COUT, NPTS)
    __shared__ _Float16 Wf[COUT * WF_OS];    // 8448 B
    __shared__ _Float16 Mld[16 * ML_PS];     // 8448 B

    const int tid = threadIdx.x;
    const int t = tid & 15;          // lane role (i in A / b in B / o in C)
    const int quad = (tid >> 4) & 3; // k-chunk select
    const int wv = tid >> 6;
    const int nbase = blockIdx.x * 16;

    const _Float16* xT16 = &ws[WS_XT];
    const float4* coords4 = (const float4*)&ws[WS_C4];

    // Stage Wf: 2 coalesced b128 loads + 2 b128 LDS writes per thread.
    {
        const int o = tid >> 4, ch = tid & 15;
        const half8 w0 = *(const half8*)&ws[WS_WF + o * 256 + ch * 16];
        const half8 w1 = *(const half8*)&ws[WS_WF + o * 256 + ch * 16 + 8];
        *(half8*)&Wf[o * WF_OS + ch * 16]     = w0;
        *(half8*)&Wf[o * WF_OS + ch * 16 + 8] = w1;
    }

    // ---- Phase B: wave wv -> points 4wv..4wv+3, one mfma_16x16x32_f16 each.
    const float cb = centers[t];
    #pragma unroll
    for (int q = 0; q < 4; ++q) {
        const int pq = wv * 4 + q;
        const int n = nbase + pq;
        const int kb = n * NNBR + 8 * quad;
        const int4 n0 = *(const int4*)&neighbors[kb];
        const int4 n1 = *(const int4*)&neighbors[kb + 4];
        const float4 m0 = *(const float4*)&mask[kb];
        const float4 m1 = *(const float4*)&mask[kb + 4];
        const float4 cc = coords4[n];
        const int nb[8] = {n0.x & (NPTS - 1), n0.y & (NPTS - 1),
                           n0.z & (NPTS - 1), n0.w & (NPTS - 1),
                           n1.x & (NPTS - 1), n1.y & (NPTS - 1),
                           n1.z & (NPTS - 1), n1.w & (NPTS - 1)};
        const float mj[8] = {m0.x, m0.y, m0.z, m0.w, m1.x, m1.y, m1.z, m1.w};
        half8 af, bf;
        #pragma unroll
        for (int j = 0; j < 8; ++j) {
            const float4 cj = coords4[nb[j]];           // group-broadcast line
            const float dx = cj.x - cc.x, dy = cj.y - cc.y, dz = cj.z - cc.z;
            const float r = sqrtf(dx * dx + dy * dy + dz * dz + 1e-12f);
            const float d = r - cb;
            bf[j] = (_Float16)__expf(-10.0f * d * d);
            const float x = (float)xT16[nb[j] * CIN + t]; // 32 B seg per group
            af[j] = (_Float16)(x * mj[j]);
        }
        floatx4 c = {0.0f, 0.0f, 0.0f, 0.0f};
        c = __builtin_amdgcn_mfma_f32_16x16x32_f16(af, bf, c, 0, 0, 0);
        // D[row=i=4quad+v][col=b=t] -> Mld[pq][t*16 + 4quad + v] (one b64)
        _Float16 h[4];
        #pragma unroll
        for (int v = 0; v < 4; ++v) h[v] = (_Float16)c[v];
        *(uint2*)&Mld[pq * ML_PS + t * 16 + 4 * quad] = *(uint2*)h;
    }
    __syncthreads();   // single barrier: Wf + Mld both cross-wave for Phase C

    // ---- Phase C (every wave, redundant): Out = W(16x256)*Mflat(256x16),
    // 8 chained MFMAs; wave wv stores its quarter of the columns.
    floatx4 acc = {0.0f, 0.0f, 0.0f, 0.0f};
    #pragma unroll
    for (int cch = 0; cch < 8; ++cch) {
        const int bi = cch * 32 + 8 * quad;
        const half8 a = *(const half8*)&Wf[t * WF_OS + bi];
        const half8 b = *(const half8*)&Mld[t * ML_PS + bi];
        acc = __builtin_amdgcn_mfma_f32_16x16x32_f16(a, b, acc, 0, 0, 0);
    }
    if (wv == (t >> 2)) {
        #pragma unroll
        for (int v = 0; v < 4; ++v)
            out[(4 * quad + v) * NPTS + nbase + t] = acc[v];
    }
}

extern "C" void kernel_launch(void* const* d_in, const int* in_sizes, int n_in,
                              void* d_out, int out_size, void* d_ws, size_t ws_size,
                              hipStream_t stream) {
    const float* input   = (const float*)d_in[0];
    const float* coords  = (const float*)d_in[1];
    const float* W       = (const float*)d_in[2];
    const float* centers = (const float*)d_in[3];
    const float* mask    = (const float*)d_in[4];
    const int*   nbr     = (const int*)d_in[5];
    float* out = (float*)d_out;
    _Float16* ws = (_Float16*)d_ws;   // ~776 KB of the 256 MB workspace

    prep_kernel<<<NPTS / 256, 256, 0, stream>>>(input, coords, W, ws);
    se3_conv_kernel<<<NPTS / 16, 256, 0, stream>>>(ws, centers, mask, nbr, out);
}